// Round 4
// baseline (399.411 us; speedup 1.0000x reference)
//
#include <hip/hip_runtime.h>

typedef _Float16 half8 __attribute__((ext_vector_type(8)));
typedef _Float16 half4_t __attribute__((ext_vector_type(4)));
typedef float f32x4 __attribute__((ext_vector_type(4)));

#define ROWS 131072   // B*S
#define BM   64       // rows per gemm block
#define NBLK 2048     // ROWS / BM

// exact-erf GELU via Abramowitz-Stegun 7.1.26 (|err| <= 1.5e-7)
__device__ __forceinline__ float gelu_erf(float y) {
  float x  = y * 0.70710678118654752440f;
  float ax = fabsf(x);
  float t  = 1.0f / (1.0f + 0.3275911f * ax);
  float poly = ((((1.061405429f * t - 1.453152027f) * t + 1.421413741f) * t
                 - 0.284496736f) * t + 0.254829592f) * t;
  float e = __expf(-ax * ax);
  float erfv = copysignf(1.0f - poly * e, x);
  return 0.5f * y * (1.0f + erfv);
}

// ------------- Kernel 1: residual add + LayerNorm -> fp16 (R1-verified) -----
__global__ __launch_bounds__(256) void ln_fuse_kernel(
    const float4* __restrict__ xa, const float4* __restrict__ xb,
    const float* __restrict__ gamma, const float* __restrict__ beta,
    half4_t* __restrict__ xn)
{
  const int lane = threadIdx.x & 63;
  const int gw   = (int)((blockIdx.x * blockDim.x + threadIdx.x) >> 6);
  const int nw   = (int)((gridDim.x * blockDim.x) >> 6);
  const float4 g  = ((const float4*)gamma)[lane];
  const float4 be = ((const float4*)beta)[lane];
  for (int row = gw; row < ROWS; row += nw) {
    size_t idx = (size_t)row * 64 + lane;
    float4 a = xa[idx], b = xb[idx];
    float4 v; v.x = a.x + b.x; v.y = a.y + b.y; v.z = a.z + b.z; v.w = a.w + b.w;
    float s  = v.x + v.y + v.z + v.w;
    float s2 = v.x * v.x + v.y * v.y + v.z * v.z + v.w * v.w;
#pragma unroll
    for (int off = 32; off > 0; off >>= 1) {
      s  += __shfl_xor(s,  off, 64);
      s2 += __shfl_xor(s2, off, 64);
    }
    float mean = s * (1.0f / 256.0f);
    float var  = s2 * (1.0f / 256.0f) - mean * mean;
    float rs   = rsqrtf(var + 1e-12f);
    half4_t h;
    h[0] = (_Float16)((v.x - mean) * rs * g.x + be.x);
    h[1] = (_Float16)((v.y - mean) * rs * g.y + be.y);
    h[2] = (_Float16)((v.z - mean) * rs * g.z + be.z);
    h[3] = (_Float16)((v.w - mean) * rs * g.w + be.w);
    xn[idx] = h;
  }
}

// ---------------- Kernel 1b: W fp32 -> fp16 (R1-verified) -------------------
__global__ __launch_bounds__(256) void wconv_kernel(
    const float4* __restrict__ W, half4_t* __restrict__ Wh)
{
  int i = blockIdx.x * 256 + threadIdx.x;
  float4 f = W[i];
  half4_t h;
  h[0] = (_Float16)f.x; h[1] = (_Float16)f.y;
  h[2] = (_Float16)f.z; h[3] = (_Float16)f.w;
  Wh[i] = h;
}

// ------- Kernel 2: GEMM, NO LDS — fragments direct from global --------------
// Block: 256 threads (4 waves, 2m x 2n), 64 rows, loops all 8 n-chunks of 128.
// A-fragments: one-time 16B loads from xn (HBM). B-fragments: 16B loads from
// Wh (512 KB, L2-resident). Zero barriers, zero LDS. All index mappings are
// verbatim from the R1-passed kernel.
__global__ __launch_bounds__(256) void gemm_direct_kernel(
    const _Float16* __restrict__ A, const _Float16* __restrict__ Bw,
    const float* __restrict__ bias, float* __restrict__ out)
{
  const int lane = threadIdx.x & 63;
  const int wave = threadIdx.x >> 6;
  const int wm = wave >> 1, wn = wave & 1;
  const size_t m0 = (size_t)blockIdx.x * BM;

  // A-fragments for this wave's 32 rows (2 row-blocks x 8 k-steps), held in VGPRs
  half8 afr[2][8];
#pragma unroll
  for (int i = 0; i < 2; ++i) {
    const size_t row = m0 + (size_t)(wm * 32 + i * 16 + (lane & 15));
#pragma unroll
    for (int ks = 0; ks < 8; ++ks)
      afr[i][ks] = *(const half8*)(A + row * 256 + ks * 32 + (lane >> 4) * 8);
  }

  const int r0 = (lane >> 4) * 4;
  const int cc = lane & 15;

#pragma unroll 1
  for (int nt = 0; nt < 8; ++nt) {
    const int n0 = nt * 128;
    f32x4 acc[2][4] = {};
#pragma unroll
    for (int ks = 0; ks < 8; ++ks) {
      half8 bf[4];
#pragma unroll
      for (int j = 0; j < 4; ++j) {
        const int col = n0 + wn * 64 + j * 16 + (lane & 15);
        bf[j] = *(const half8*)(Bw + (size_t)col * 256 + ks * 32 + (lane >> 4) * 8);
      }
#pragma unroll
      for (int i = 0; i < 2; ++i)
#pragma unroll
        for (int j = 0; j < 4; ++j)
          acc[i][j] = __builtin_amdgcn_mfma_f32_16x16x32_f16(afr[i][ks], bf[j], acc[i][j], 0, 0, 0);
    }
#pragma unroll
    for (int j = 0; j < 4; ++j) {
      const int col = n0 + wn * 64 + j * 16 + cc;
      const float bv = bias[col];
#pragma unroll
      for (int i = 0; i < 2; ++i) {
        const size_t row = m0 + (size_t)(wm * 32 + i * 16 + r0);
        float* op = out + row * 1024 + col;
#pragma unroll
        for (int r = 0; r < 4; ++r)
          op[(size_t)r * 1024] = gelu_erf(acc[i][j][r] + bv);
      }
    }
  }
}

extern "C" void kernel_launch(void* const* d_in, const int* in_sizes, int n_in,
                              void* d_out, int out_size, void* d_ws, size_t ws_size,
                              hipStream_t stream) {
  const float* x399  = (const float*)d_in[0];
  const float* x365  = (const float*)d_in[1];
  const float* gamma = (const float*)d_in[2];
  const float* beta  = (const float*)d_in[3];
  const float* W     = (const float*)d_in[4];
  const float* bias  = (const float*)d_in[5];
  float* out = (float*)d_out;

  _Float16* xn = (_Float16*)d_ws;                 // 131072*256*2 = 64 MiB
  _Float16* Wh = xn + (size_t)ROWS * 256;         // 512 KiB

  ln_fuse_kernel<<<2048, 256, 0, stream>>>(
      (const float4*)x399, (const float4*)x365, gamma, beta, (half4_t*)xn);
  wconv_kernel<<<256, 256, 0, stream>>>((const float4*)W, (half4_t*)Wh);
  gemm_direct_kernel<<<NBLK, 256, 0, stream>>>(xn, Wh, bias, out);
}